// Round 2
// baseline (276.838 us; speedup 1.0000x reference)
//
#include <hip/hip_runtime.h>
#include <hip/hip_bf16.h>

#define NBATCH 256
#define NT 512
#define ND 256
#define NROWS (NBATCH * NT)   // 131072

typedef __attribute__((ext_vector_type(8))) short short8;
typedef __attribute__((ext_vector_type(4))) float floatx4;

__device__ __forceinline__ unsigned short f2bf(float x) {
    // round-to-nearest-even fp32 -> bf16
    unsigned int u = __float_as_uint(x);
    u += 0x7FFFu + ((u >> 16) & 1u);
    return (unsigned short)(u >> 16);
}

// prep: W fp32 [D,D] -> bf16 (RTNE) in workspace
__global__ void __launch_bounds__(256) prep_kernel(
    const float* __restrict__ W, unsigned short* __restrict__ wbf)
{
    int i = (blockIdx.x * 256 + threadIdx.x) * 4;   // 16384 threads * 4 = 65536
    float4 f = *(const float4*)(W + i);
    ushort4 o;
    o.x = f2bf(f.x); o.y = f2bf(f.y); o.z = f2bf(f.z); o.w = f2bf(f.w);
    *(ushort4*)(wbf + i) = o;
}

// Kernel 1: scores[bt] = sum_e tanh( sum_d ip[bt,d]*W[e,d] + bias[e] ) * ctx[e]
// One wave: M=32 rows (2 MFMA A-tiles), loops 16 n-blocks, K=256 (8 MFMA steps).
// A-frags converted fp32->bf16 once, register-resident; W(bf16) from L1/L2.
__global__ void __launch_bounds__(256) scores_kernel(
    const float* __restrict__ ip,             // [B*T, D] fp32
    const unsigned short* __restrict__ wbf,   // [D, D] (e,d) bf16
    const float* __restrict__ bias,           // [D] fp32
    const float* __restrict__ ctx,            // [D] fp32
    float* __restrict__ scores)               // [B*T] fp32
{
    const int lane = threadIdx.x & 63;
    const int wid  = threadIdx.x >> 6;
    const int m = lane & 15;          // A row / B col within tile
    const int q = lane >> 4;          // k-quad
    const long row0 = ((long)blockIdx.x * 4 + wid) * 32;

    // Load + convert A fragments: a[tile][s] covers row (row0 + tile*16 + m),
    // k = q*8 + s*32 .. +8
    short8 a[2][8];
#pragma unroll
    for (int tile = 0; tile < 2; ++tile) {
        const float* ar = ip + (row0 + tile * 16 + m) * ND + q * 8;
#pragma unroll
        for (int s = 0; s < 8; ++s) {
            float4 f0 = *(const float4*)(ar + s * 32);
            float4 f1 = *(const float4*)(ar + s * 32 + 4);
            short8 v;
            v[0] = (short)f2bf(f0.x); v[1] = (short)f2bf(f0.y);
            v[2] = (short)f2bf(f0.z); v[3] = (short)f2bf(f0.w);
            v[4] = (short)f2bf(f1.x); v[5] = (short)f2bf(f1.y);
            v[6] = (short)f2bf(f1.z); v[7] = (short)f2bf(f1.w);
            a[tile][s] = v;
        }
    }

    float sc0[4] = {0.f, 0.f, 0.f, 0.f};
    float sc1[4] = {0.f, 0.f, 0.f, 0.f};

#pragma unroll 1
    for (int nb = 0; nb < 16; ++nb) {
        const int e = nb * 16 + m;                    // h-column this lane covers
        const short8* wr = (const short8*)(wbf + e * ND + q * 8);
        short8 w[8];
#pragma unroll
        for (int s = 0; s < 8; ++s) w[s] = wr[s * 4];   // stride 32 elems
        floatx4 acc0 = {0.f, 0.f, 0.f, 0.f};
        floatx4 acc1 = {0.f, 0.f, 0.f, 0.f};
#pragma unroll
        for (int s = 0; s < 8; ++s) {
            acc0 = __builtin_amdgcn_mfma_f32_16x16x32_bf16(a[0][s], w[s], acc0, 0, 0, 0);
            acc1 = __builtin_amdgcn_mfma_f32_16x16x32_bf16(a[1][s], w[s], acc1, 0, 0, 0);
        }
        const float be = bias[e];
        const float ce = ctx[e];
#pragma unroll
        for (int r = 0; r < 4; ++r) {                 // acc[r] = D[row=q*4+r][col=m]
            float x0 = acc0[r] + be;
            float x1 = acc1[r] + be;
            // tanh(x) = 1 - 2/(exp(2x)+1), valid for all x, no overflow
            sc0[r] += (1.f - 2.f / (__expf(2.f * x0) + 1.f)) * ce;
            sc1[r] += (1.f - 2.f / (__expf(2.f * x1) + 1.f)) * ce;
        }
    }
    // Sum over 16 e-columns held by lanes with same q (xor lane bits 0..3)
#pragma unroll
    for (int off = 8; off >= 1; off >>= 1) {
#pragma unroll
        for (int r = 0; r < 4; ++r) {
            sc0[r] += __shfl_xor(sc0[r], off, 64);
            sc1[r] += __shfl_xor(sc1[r], off, 64);
        }
    }
    if (m == 0) {
#pragma unroll
        for (int r = 0; r < 4; ++r) {
            scores[row0 + q * 4 + r]      = sc0[r];
            scores[row0 + 16 + q * 4 + r] = sc1[r];
        }
    }
}

// Kernel 2: per batch, softmax over T then sent[d] = sum_t attn[t]*ip[b,t,d] (all fp32)
__global__ void __launch_bounds__(1024) attn_kernel(
    const float* __restrict__ ip,       // [B,T,D] fp32
    const float* __restrict__ scores,   // [B,T] fp32
    float* __restrict__ out)            // [B,D] fp32
{
    __shared__ float attn[NT];
    __shared__ float red[16];
    __shared__ float partial[16][ND];

    const int b = blockIdx.x;
    const int tid = threadIdx.x;
    const int lane = tid & 63;
    const int wid = tid >> 6;

    // --- softmax over scores[b,:] by threads 0..511 (8 waves) ---
    float s = 0.f;
    if (tid < NT) {
        s = scores[(long)b * NT + tid];
        float mx = s;
#pragma unroll
        for (int off = 32; off >= 1; off >>= 1) mx = fmaxf(mx, __shfl_xor(mx, off, 64));
        if (lane == 0) red[wid] = mx;       // wid 0..7
    }
    __syncthreads();
    float mx = red[0];
#pragma unroll
    for (int i = 1; i < 8; ++i) mx = fmaxf(mx, red[i]);
    float ev = 0.f;
    if (tid < NT) {
        ev = __expf(s - mx);
        float sm = ev;
#pragma unroll
        for (int off = 32; off >= 1; off >>= 1) sm += __shfl_xor(sm, off, 64);
        if (lane == 0) red[8 + wid] = sm;   // separate slots: no WAR race
    }
    __syncthreads();
    float sum = 0.f;
#pragma unroll
    for (int i = 0; i < 8; ++i) sum += red[8 + i];
    if (tid < NT) attn[tid] = ev / sum;
    __syncthreads();

    // --- weighted sum: thread = (d-group dg of 4 floats, t-slice ts of 32) ---
    const int dg = lane;                // 0..63 -> float4 column
    const int ts = wid;                 // 0..15 -> t range [ts*32, ts*32+32)
    const float4* base = (const float4*)(ip + (long)b * NT * ND) + dg;
    float a0 = 0.f, a1 = 0.f, a2 = 0.f, a3 = 0.f;
#pragma unroll 4
    for (int t = ts * 32; t < ts * 32 + 32; ++t) {
        float w = attn[t];
        float4 v = base[t * 64];        // row stride = 64 float4
        a0 += w * v.x; a1 += w * v.y; a2 += w * v.z; a3 += w * v.w;
    }
    partial[ts][dg * 4 + 0] = a0;
    partial[ts][dg * 4 + 1] = a1;
    partial[ts][dg * 4 + 2] = a2;
    partial[ts][dg * 4 + 3] = a3;
    __syncthreads();
    if (tid < ND) {
        float r = 0.f;
#pragma unroll
        for (int i = 0; i < 16; ++i) r += partial[i][tid];
        out[(long)b * ND + tid] = r;
    }
}

extern "C" void kernel_launch(void* const* d_in, const int* in_sizes, int n_in,
                              void* d_out, int out_size, void* d_ws, size_t ws_size,
                              hipStream_t stream) {
    const float* ip   = (const float*)d_in[0];
    const float* W    = (const float*)d_in[1];
    const float* bias = (const float*)d_in[2];
    const float* ctx  = (const float*)d_in[3];

    unsigned short* wbf = (unsigned short*)d_ws;                 // 128 KB
    float* scores = (float*)((char*)d_ws + ND * ND * sizeof(unsigned short)); // 512 KB

    prep_kernel<<<64, 256, 0, stream>>>(W, wbf);
    scores_kernel<<<NROWS / 128, 256, 0, stream>>>(ip, wbf, bias, ctx, scores);
    attn_kernel<<<NBATCH, 1024, 0, stream>>>(ip, scores, (float*)d_out);
}

// Round 3
// 250.801 us; speedup vs baseline: 1.1038x; 1.1038x over previous
//
#include <hip/hip_runtime.h>
#include <hip/hip_bf16.h>

#define NBATCH 256
#define NT 512
#define ND 256

typedef __attribute__((ext_vector_type(8))) short short8;
typedef __attribute__((ext_vector_type(4))) float floatx4;

__device__ __forceinline__ unsigned short f2bf(float x) {
    // round-to-nearest-even fp32 -> bf16
    unsigned int u = __float_as_uint(x);
    u += 0x7FFFu + ((u >> 16) & 1u);
    return (unsigned short)(u >> 16);
}

// prep: W fp32 [D,D] -> bf16 (RTNE), row-major, in workspace
__global__ void __launch_bounds__(256) prep_kernel(
    const float* __restrict__ W, unsigned short* __restrict__ wbf)
{
    int i = (blockIdx.x * 256 + threadIdx.x) * 4;
    float4 f = *(const float4*)(W + i);
    ushort4 o;
    o.x = f2bf(f.x); o.y = f2bf(f.y); o.z = f2bf(f.z); o.w = f2bf(f.w);
    *(ushort4*)(wbf + i) = o;
}

// Fused: per batch b (one block of 1024 thr = 16 waves):
//   1) scores[t] = sum_e tanh(sum_d ip[b,t,d]*W[e,d] + bias[e]) * ctx[e]  (MFMA bf16)
//      - W staged into LDS in MFMA-frag order, 32KB quarters (4 stages)
//      - each wave owns 32 rows (2 MFMA A-tiles), A-frags in registers
//   2) softmax over T=512 in-block
//   3) out[b,d] = sum_t attn[t]*ip[b,t,d]  (ip re-read; L3-warm)
__global__ void __launch_bounds__(1024) fused_kernel(
    const float* __restrict__ ip,             // [B,T,D] fp32
    const unsigned short* __restrict__ wbf,   // [D,D] (e,d) bf16
    const float* __restrict__ bias,           // [D] fp32
    const float* __restrict__ ctx,            // [D] fp32
    float* __restrict__ out)                  // [B,D] fp32
{
    __shared__ __align__(16) char wsm[32768]; // W quarter (frag order); reused as partial[]
    __shared__ float sc_buf[NT];
    __shared__ float attn_s[NT];
    __shared__ float red[16];
    __shared__ float bias_s[ND];
    __shared__ float ctx_s[ND];

    const int tid  = threadIdx.x;
    const int lane = tid & 63;
    const int wv   = tid >> 6;        // wave 0..15
    const int m    = lane & 15;       // A row / W e-col within tile
    const int q    = lane >> 4;       // k-quad
    const int b    = blockIdx.x;
    const long row0 = (long)b * NT + wv * 32;

    if (tid < ND) { bias_s[tid] = bias[tid]; ctx_s[tid] = ctx[tid]; }

    // ---- A fragments: 32 rows per wave, fp32 -> bf16, register-resident ----
    short8 a[2][8];
#pragma unroll
    for (int tile = 0; tile < 2; ++tile) {
        const float* ar = ip + (row0 + tile * 16 + m) * ND + q * 8;
#pragma unroll
        for (int s = 0; s < 8; ++s) {
            float4 f0 = *(const float4*)(ar + s * 32);
            float4 f1 = *(const float4*)(ar + s * 32 + 4);
            short8 v;
            v[0] = (short)f2bf(f0.x); v[1] = (short)f2bf(f0.y);
            v[2] = (short)f2bf(f0.z); v[3] = (short)f2bf(f0.w);
            v[4] = (short)f2bf(f1.x); v[5] = (short)f2bf(f1.y);
            v[6] = (short)f2bf(f1.z); v[7] = (short)f2bf(f1.w);
            a[tile][s] = v;
        }
    }

    float sc0[4] = {0.f, 0.f, 0.f, 0.f};
    float sc1[4] = {0.f, 0.f, 0.f, 0.f};
    const short8* wch = (const short8*)wbf;   // 16B chunks, row-major

#pragma unroll 1
    for (int stage = 0; stage < 4; ++stage) {
        if (stage) __syncthreads();           // prior quarter's reads complete
        // stage 4 nb-groups of W (2048 chunks x 16B = 32KB) in frag order:
        // chunk c = nb*512 + s*64 + q*16 + m  <->  wbf[e=nb*16+m][k=q*8+s*32 ..+8]
#pragma unroll
        for (int u = 0; u < 2; ++u) {
            int c  = stage * 2048 + tid + u * 1024;
            int cm = c & 15, cq = (c >> 4) & 3, cs = (c >> 6) & 7, cnb = c >> 9;
            int G  = ((cnb * 16 + cm) << 5) + cq + (cs << 2);
            *(short8*)(wsm + ((tid + u * 1024) << 4)) = wch[G];
        }
        __syncthreads();

#pragma unroll 1
        for (int nbl = 0; nbl < 4; ++nbl) {
            const int nb = stage * 4 + nbl;
            const int e  = nb * 16 + m;
            const char* wbase = wsm + (((nbl << 9) + lane) << 4);
            short8 w[8];
#pragma unroll
            for (int s = 0; s < 8; ++s)
                w[s] = *(const short8*)(wbase + (s << 10));   // lane-linear: conflict-free
            floatx4 acc0 = {0.f, 0.f, 0.f, 0.f};
            floatx4 acc1 = {0.f, 0.f, 0.f, 0.f};
#pragma unroll
            for (int s = 0; s < 8; ++s) {
                acc0 = __builtin_amdgcn_mfma_f32_16x16x32_bf16(a[0][s], w[s], acc0, 0, 0, 0);
                acc1 = __builtin_amdgcn_mfma_f32_16x16x32_bf16(a[1][s], w[s], acc1, 0, 0, 0);
            }
            const float be = bias_s[e];
            const float ce = ctx_s[e];
#pragma unroll
            for (int r = 0; r < 4; ++r) {     // acc[r] = D[row=q*4+r][col=m]
                float x0 = acc0[r] + be;
                float x1 = acc1[r] + be;
                sc0[r] += (1.f - 2.f / (__expf(2.f * x0) + 1.f)) * ce;
                sc1[r] += (1.f - 2.f / (__expf(2.f * x1) + 1.f)) * ce;
            }
        }
    }

    // sum over 16 e-cols spread across lanes sharing a quad
#pragma unroll
    for (int off = 8; off >= 1; off >>= 1) {
#pragma unroll
        for (int r = 0; r < 4; ++r) {
            sc0[r] += __shfl_xor(sc0[r], off, 64);
            sc1[r] += __shfl_xor(sc1[r], off, 64);
        }
    }
    if (m == 0) {
#pragma unroll
        for (int r = 0; r < 4; ++r) {
            sc_buf[wv * 32 + q * 4 + r]      = sc0[r];
            sc_buf[wv * 32 + 16 + q * 4 + r] = sc1[r];
        }
    }
    __syncthreads();

    // ---- softmax over sc_buf[0..511] (threads 0..511) ----
    float s = 0.f;
    if (tid < NT) {
        s = sc_buf[tid];
        float mx = s;
#pragma unroll
        for (int off = 32; off >= 1; off >>= 1) mx = fmaxf(mx, __shfl_xor(mx, off, 64));
        if (lane == 0) red[wv] = mx;          // wv 0..7
    }
    __syncthreads();
    float mx = red[0];
#pragma unroll
    for (int i = 1; i < 8; ++i) mx = fmaxf(mx, red[i]);
    float ev = 0.f;
    if (tid < NT) {
        ev = __expf(s - mx);
        float sm = ev;
#pragma unroll
        for (int off = 32; off >= 1; off >>= 1) sm += __shfl_xor(sm, off, 64);
        if (lane == 0) red[8 + wv] = sm;
    }
    __syncthreads();
    float sum = 0.f;
#pragma unroll
    for (int i = 0; i < 8; ++i) sum += red[8 + i];
    if (tid < NT) attn_s[tid] = ev / sum;
    __syncthreads();                          // also: all W reads done -> wsm reusable

    // ---- weighted sum: thread = (d-group of 4 floats, t-slice of 32) ----
    float (*partial)[ND] = (float (*)[ND])wsm;   // 16x256x4 = 16KB, aliases W region
    const int dg = lane;                      // float4 column 0..63
    const int ts = wv;                        // t range [ts*32, ts*32+32)
    const float4* base = (const float4*)(ip + (long)b * NT * ND) + dg;
    float a0 = 0.f, a1 = 0.f, a2 = 0.f, a3 = 0.f;
#pragma unroll 4
    for (int t = ts * 32; t < ts * 32 + 32; ++t) {
        float w = attn_s[t];
        float4 v = base[t * 64];              // row stride = 64 float4; coalesced
        a0 += w * v.x; a1 += w * v.y; a2 += w * v.z; a3 += w * v.w;
    }
    partial[ts][dg * 4 + 0] = a0;
    partial[ts][dg * 4 + 1] = a1;
    partial[ts][dg * 4 + 2] = a2;
    partial[ts][dg * 4 + 3] = a3;
    __syncthreads();
    if (tid < ND) {
        float r = 0.f;
#pragma unroll
        for (int i = 0; i < 16; ++i) r += partial[i][tid];
        out[(long)b * ND + tid] = r;
    }
}

extern "C" void kernel_launch(void* const* d_in, const int* in_sizes, int n_in,
                              void* d_out, int out_size, void* d_ws, size_t ws_size,
                              hipStream_t stream) {
    const float* ip   = (const float*)d_in[0];
    const float* W    = (const float*)d_in[1];
    const float* bias = (const float*)d_in[2];
    const float* ctx  = (const float*)d_in[3];

    unsigned short* wbf = (unsigned short*)d_ws;  // 128 KB

    prep_kernel<<<64, 256, 0, stream>>>(W, wbf);
    fused_kernel<<<NBATCH, 1024, 0, stream>>>(ip, wbf, bias, ctx, (float*)d_out);
}

// Round 4
// 241.058 us; speedup vs baseline: 1.1484x; 1.0404x over previous
//
#include <hip/hip_runtime.h>
#include <hip/hip_bf16.h>

#define NBATCH 256
#define NT 512
#define ND 256
#define NROWS (NBATCH * NT)

typedef __attribute__((ext_vector_type(8))) short short8;
typedef __attribute__((ext_vector_type(4))) float floatx4;

__device__ __forceinline__ unsigned short f2bf(float x) {
    // round-to-nearest-even fp32 -> bf16
    unsigned int u = __float_as_uint(x);
    u += 0x7FFFu + ((u >> 16) & 1u);
    return (unsigned short)(u >> 16);
}

// prep: W fp32 [D,D] -> bf16 (RTNE), row-major, in workspace
__global__ void __launch_bounds__(256) prep_kernel(
    const float* __restrict__ W, unsigned short* __restrict__ wbf)
{
    int i = (blockIdx.x * 256 + threadIdx.x) * 4;
    float4 f = *(const float4*)(W + i);
    ushort4 o;
    o.x = f2bf(f.x); o.y = f2bf(f.y); o.z = f2bf(f.z); o.w = f2bf(f.w);
    *(ushort4*)(wbf + i) = o;
}

// scores[bt] = sum_e tanh(sum_d ip[bt,d]*W[e,d] + bias[e]) * ctx[e]
// 1024 blocks x 256 thr (4 waves). Wave owns 32 rows (2 MFMA A-tiles),
// A-frags register-resident (64 VGPR). W staged to LDS in frag order,
// 32KB quarters. launch_bounds(256,2): no spills (~150 VGPR).
__global__ void __launch_bounds__(256, 2) scores_kernel(
    const float* __restrict__ ip,             // [B*T, D] fp32
    const unsigned short* __restrict__ wbf,   // [D,D] (e,d) bf16
    const float* __restrict__ bias,           // [D] fp32
    const float* __restrict__ ctx,            // [D] fp32
    float* __restrict__ scores)               // [B*T] fp32
{
    __shared__ __align__(16) char wsm[32768];
    __shared__ float bias_s[ND];
    __shared__ float ctx_s[ND];

    const int tid  = threadIdx.x;
    const int lane = tid & 63;
    const int wv   = tid >> 6;        // wave 0..3
    const int m    = lane & 15;       // A row / W e-col within tile
    const int q    = lane >> 4;       // k-quad
    const long row0 = (long)blockIdx.x * 128 + wv * 32;

    bias_s[tid] = bias[tid];
    ctx_s[tid]  = ctx[tid];

    // A fragments: 32 rows/wave, fp32 -> bf16, register-resident
    short8 a[2][8];
#pragma unroll
    for (int tile = 0; tile < 2; ++tile) {
        const float* ar = ip + (row0 + tile * 16 + m) * ND + q * 8;
#pragma unroll
        for (int s = 0; s < 8; ++s) {
            float4 f0 = *(const float4*)(ar + s * 32);
            float4 f1 = *(const float4*)(ar + s * 32 + 4);
            short8 v;
            v[0] = (short)f2bf(f0.x); v[1] = (short)f2bf(f0.y);
            v[2] = (short)f2bf(f0.z); v[3] = (short)f2bf(f0.w);
            v[4] = (short)f2bf(f1.x); v[5] = (short)f2bf(f1.y);
            v[6] = (short)f2bf(f1.z); v[7] = (short)f2bf(f1.w);
            a[tile][s] = v;
        }
    }

    float sc0[4] = {0.f, 0.f, 0.f, 0.f};
    float sc1[4] = {0.f, 0.f, 0.f, 0.f};
    const short8* wch = (const short8*)wbf;   // 16B chunks, row-major

#pragma unroll 1
    for (int stage = 0; stage < 4; ++stage) {
        if (stage) __syncthreads();
        // stage 2048 chunks (32KB) in frag order:
        // local chunk c' = nb'*512 + s*64 + q*16 + m  <->  W[e=(stage*4+nb')*16+m][k=q*8+s*32..+8]
#pragma unroll
        for (int u = 0; u < 8; ++u) {
            int c  = stage * 2048 + tid + u * 256;
            int cm = c & 15, cq = (c >> 4) & 3, cs = (c >> 6) & 7, cnb = c >> 9;
            int G  = ((cnb * 16 + cm) << 5) + cq + (cs << 2);
            *(short8*)(wsm + ((tid + u * 256) << 4)) = wch[G];
        }
        __syncthreads();

#pragma unroll 1
        for (int nbl = 0; nbl < 4; ++nbl) {
            const int e  = (stage * 4 + nbl) * 16 + m;
            const char* wbase = wsm + (((nbl << 9) + lane) << 4);
            short8 w[8];
#pragma unroll
            for (int s = 0; s < 8; ++s)
                w[s] = *(const short8*)(wbase + (s << 10));   // lane-linear, conflict-free
            floatx4 acc0 = {0.f, 0.f, 0.f, 0.f};
            floatx4 acc1 = {0.f, 0.f, 0.f, 0.f};
#pragma unroll
            for (int s = 0; s < 8; ++s) {
                acc0 = __builtin_amdgcn_mfma_f32_16x16x32_bf16(a[0][s], w[s], acc0, 0, 0, 0);
                acc1 = __builtin_amdgcn_mfma_f32_16x16x32_bf16(a[1][s], w[s], acc1, 0, 0, 0);
            }
            const float be = bias_s[e];
            const float ce = ctx_s[e];
#pragma unroll
            for (int r = 0; r < 4; ++r) {     // acc[r] = D[row=q*4+r][col=m]
                float x0 = acc0[r] + be;
                float x1 = acc1[r] + be;
                sc0[r] += (1.f - 2.f / (__expf(2.f * x0) + 1.f)) * ce;
                sc1[r] += (1.f - 2.f / (__expf(2.f * x1) + 1.f)) * ce;
            }
        }
    }

    // sum over 16 e-cols spread across lanes sharing a quad
#pragma unroll
    for (int off = 8; off >= 1; off >>= 1) {
#pragma unroll
        for (int r = 0; r < 4; ++r) {
            sc0[r] += __shfl_xor(sc0[r], off, 64);
            sc1[r] += __shfl_xor(sc1[r], off, 64);
        }
    }
    if (m == 0) {
#pragma unroll
        for (int r = 0; r < 4; ++r) {
            scores[row0 + q * 4 + r]      = sc0[r];
            scores[row0 + 16 + q * 4 + r] = sc1[r];
        }
    }
}

// wsum: block (b, dquad of 64 floats). In-block softmax over scores[b,:],
// then out[b, d] = sum_t attn[t] * ip[b,t,d] for d in the 64-float slice.
__global__ void __launch_bounds__(256) wsum_kernel(
    const float* __restrict__ ip,       // [B,T,D] fp32
    const float* __restrict__ scores,   // [B,T] fp32
    float* __restrict__ out)            // [B,D] fp32
{
    __shared__ float attn_s[NT];
    __shared__ float red[8];
    __shared__ float partial[16][64];

    const int b  = blockIdx.x >> 2;
    const int dq = blockIdx.x & 3;      // d-slice: [dq*64, dq*64+64)
    const int tid  = threadIdx.x;
    const int lane = tid & 63;
    const int wv   = tid >> 6;          // wave 0..3

    // softmax: each thread handles scores tid and tid+256
    float s0 = scores[(long)b * NT + tid];
    float s1 = scores[(long)b * NT + tid + 256];
    float mx = fmaxf(s0, s1);
#pragma unroll
    for (int off = 32; off >= 1; off >>= 1) mx = fmaxf(mx, __shfl_xor(mx, off, 64));
    if (lane == 0) red[wv] = mx;
    __syncthreads();
    mx = fmaxf(fmaxf(red[0], red[1]), fmaxf(red[2], red[3]));
    float e0 = __expf(s0 - mx), e1 = __expf(s1 - mx);
    float sm = e0 + e1;
#pragma unroll
    for (int off = 32; off >= 1; off >>= 1) sm += __shfl_xor(sm, off, 64);
    __syncthreads();                    // red max-reads done before rewrite
    if (lane == 0) red[4 + wv] = sm;
    __syncthreads();
    sm = red[4] + red[5] + red[6] + red[7];
    float inv = 1.f / sm;
    attn_s[tid]       = e0 * inv;
    attn_s[tid + 256] = e1 * inv;
    __syncthreads();

    // weighted sum: thread = (dg float4 in slice: 0..15, t-slice ts: 0..15 of 32 t)
    const int dg = tid & 15;
    const int ts = tid >> 4;
    const float4* base = (const float4*)(ip + (long)b * NT * ND + dq * 64) + dg;
    float a0 = 0.f, a1 = 0.f, a2 = 0.f, a3 = 0.f;
#pragma unroll 8
    for (int t = ts * 32; t < ts * 32 + 32; ++t) {
        float w = attn_s[t];
        float4 v = base[t * 64];        // row stride = 64 float4; coalesced 64B x 4 rows/instr
        a0 += w * v.x; a1 += w * v.y; a2 += w * v.z; a3 += w * v.w;
    }
    partial[ts][dg * 4 + 0] = a0;
    partial[ts][dg * 4 + 1] = a1;
    partial[ts][dg * 4 + 2] = a2;
    partial[ts][dg * 4 + 3] = a3;
    __syncthreads();
    if (tid < 64) {
        float r = 0.f;
#pragma unroll
        for (int i = 0; i < 16; ++i) r += partial[i][tid];
        out[(long)b * ND + dq * 64 + tid] = r;
    }
}

extern "C" void kernel_launch(void* const* d_in, const int* in_sizes, int n_in,
                              void* d_out, int out_size, void* d_ws, size_t ws_size,
                              hipStream_t stream) {
    const float* ip   = (const float*)d_in[0];
    const float* W    = (const float*)d_in[1];
    const float* bias = (const float*)d_in[2];
    const float* ctx  = (const float*)d_in[3];

    unsigned short* wbf = (unsigned short*)d_ws;  // 128 KB
    float* scores = (float*)((char*)d_ws + ND * ND * sizeof(unsigned short)); // 512 KB

    prep_kernel<<<64, 256, 0, stream>>>(W, wbf);
    scores_kernel<<<NROWS / 128, 256, 0, stream>>>(ip, wbf, bias, ctx, scores);
    wsum_kernel<<<NBATCH * 4, 256, 0, stream>>>(ip, scores, (float*)d_out);
}